// Round 9
// baseline (195.860 us; speedup 1.0000x reference)
//
#include <hip/hip_runtime.h>
#include <cstdint>

#define B_ 4
#define S_ 4096
#define D_ 512
#define M_ (B_*S_)   // 16384 rows

typedef _Float16 f16;
typedef _Float16 f16x8 __attribute__((ext_vector_type(8)));
typedef _Float16 f16x2 __attribute__((ext_vector_type(2)));
typedef float    f32x4 __attribute__((ext_vector_type(4)));

typedef __attribute__((address_space(1))) void* as1p;
typedef __attribute__((address_space(3))) void* as3p;

__device__ __forceinline__ void gl2lds16(const void* g, void* l) {
    __builtin_amdgcn_global_load_lds((as1p)g, (as3p)l, 16, 0, 0);
}

union f16pack { f16x8 v8; f16x2 v2[4]; };

// ---------------- k1: blocks 0..255 = xs cast + per-block column partials;
//     blocks 256..447 = weight GEMMs with direct global fp32 operand reads (no transpose buffers)
//     z==0: Wvl = Wl@Wv (f16 out) + bvl ; z==1: Mm = Wk^T Wq + t1,t2,t12 ; z==2: MT = Wq^T Wk ----------------
__global__ __launch_bounds__(256) void k1_kernel(
    const float* __restrict__ xs,
    const float* __restrict__ Wv, const float* __restrict__ Wk,
    const float* __restrict__ Wq, const float* __restrict__ Wl,
    const float* __restrict__ bv, const float* __restrict__ bk,
    const float* __restrict__ bq,
    f16* __restrict__ xs_h, float* __restrict__ xpart,
    f16* __restrict__ WvlH, float* __restrict__ bvlG,
    float* __restrict__ Mm, float* __restrict__ MT,
    float* __restrict__ t1, float* __restrict__ t2, float* __restrict__ t12)
{
    __shared__ float smem[2048];   // xs half only: red[4][512] (8KB)
    const int t = threadIdx.x;
    if (blockIdx.x < 256) {
        const int blk = blockIdx.x;
        const int w = t >> 6, l = t & 63;
        const int col = l * 8;
        float acc[8] = {0,0,0,0,0,0,0,0};
        for (int c = 0; c < 16; c++) {
            int row = blk*64 + c*4 + w;
            const float4* p = (const float4*)(xs + (size_t)row*512 + col);
            float4 a = p[0], b = p[1];
            f16x8 o;
            o[0]=(f16)a.x; o[1]=(f16)a.y; o[2]=(f16)a.z; o[3]=(f16)a.w;
            o[4]=(f16)b.x; o[5]=(f16)b.y; o[6]=(f16)b.z; o[7]=(f16)b.w;
            *(f16x8*)(xs_h + (size_t)row*512 + col) = o;
            acc[0]+=a.x; acc[1]+=a.y; acc[2]+=a.z; acc[3]+=a.w;
            acc[4]+=b.x; acc[5]+=b.y; acc[6]+=b.z; acc[7]+=b.w;
        }
        #pragma unroll
        for (int q = 0; q < 8; q++) smem[w*512 + col + q] = acc[q];
        __syncthreads();
        #pragma unroll
        for (int k = 0; k < 2; k++) {
            int c = t + k*256;
            xpart[(size_t)blk*512 + c] = smem[c] + smem[512+c] + smem[1024+c] + smem[1536+c];
        }
        return;
    }
    // ---- weight GEMM half ----
    const int v = blockIdx.x - 256;
    const int z = v >> 6, tile_id = v & 63;
    const int bx = tile_id & 7, by = tile_id >> 3;
    const int i0 = bx*64, j0 = by*64;
    const int lane = t & 63, wid = t >> 6;
    const int wm = (wid & 1)*32, wn = (wid >> 1)*32;
    // A: z==0 -> Wl rows (direct); z==1 -> Wk cols (transposed); z==2 -> Wq cols
    // B: z==0 -> Wv cols; z==1 -> Wq cols; z==2 -> Wk cols
    const float* Asrc = (z == 0) ? Wl : ((z == 1) ? Wk : Wq);
    const float* Bsrc = (z == 0) ? Wv : ((z == 1) ? Wq : Wk);
    const bool aDirect = (z == 0);
    const bool doT1 = (z == 1) && (bx == 0);
    const bool doT2 = (z == 1) && (by == 0);
    const int ar = lane & 15, kg = lane >> 4;
    const int jj = t >> 2, kq = (t & 3)*8;

    f32x4 acc[2][2] = {};
    float t1a = 0.f, t2a = 0.f;

    for (int k0 = 0; k0 < 512; k0 += 32) {
        const int kb = k0 + kg*8;
        f16x8 af[2], bf[2];
        #pragma unroll
        for (int i = 0; i < 2; i++) {
            const int row = i0 + wm + ar + i*16;
            f16x8 o;
            if (aDirect) {
                const float4* p = (const float4*)(Asrc + (size_t)row*512 + kb);
                float4 x0 = p[0], x1 = p[1];
                o[0]=(f16)x0.x; o[1]=(f16)x0.y; o[2]=(f16)x0.z; o[3]=(f16)x0.w;
                o[4]=(f16)x1.x; o[5]=(f16)x1.y; o[6]=(f16)x1.z; o[7]=(f16)x1.w;
            } else {
                #pragma unroll
                for (int q = 0; q < 8; q++) o[q] = (f16)Asrc[(size_t)(kb+q)*512 + row];
            }
            af[i] = o;
        }
        #pragma unroll
        for (int j = 0; j < 2; j++) {
            const int colj = j0 + wn + ar + j*16;
            f16x8 o;
            #pragma unroll
            for (int q = 0; q < 8; q++) o[q] = (f16)Bsrc[(size_t)(kb+q)*512 + colj];
            bf[j] = o;
        }
        #pragma unroll
        for (int i = 0; i < 2; i++)
            #pragma unroll
            for (int j = 0; j < 2; j++)
                acc[i][j] = __builtin_amdgcn_mfma_f32_16x16x32_f16(af[i], bf[j], acc[i][j], 0, 0, 0);
        if (doT1) {   // t1[e] = sum_k Wq[k][e]*bk[k]  (e = j0+jj)
            #pragma unroll
            for (int q = 0; q < 8; q++)
                t1a += Bsrc[(size_t)(k0+kq+q)*512 + j0 + jj] * bk[k0+kq+q];
        }
        if (doT2) {   // t2[j] = sum_k Wk[k][j]*bq[k]  (j = i0+jj)
            #pragma unroll
            for (int q = 0; q < 8; q++)
                t2a += Asrc[(size_t)(k0+kq+q)*512 + i0 + jj] * bq[k0+kq+q];
        }
    }

    const int rb = wm + ((lane >> 4) << 2);
    const int cb = wn + (lane & 15);
    if (z == 0) {
        #pragma unroll
        for (int i = 0; i < 2; i++)
            #pragma unroll
            for (int j = 0; j < 2; j++)
                #pragma unroll
                for (int r = 0; r < 4; r++)
                    WvlH[(size_t)(i0 + rb + i*16 + r)*512 + j0 + cb + j*16] = (f16)acc[i][j][r];
        if (by == 0) {
            int r = t >> 2, part = t & 3;
            const float4* wr = (const float4*)(Wl + (size_t)(i0+r)*512 + part*128);
            const float4* bp = (const float4*)(bv + part*128);
            float s = 0.f;
            #pragma unroll 8
            for (int q = 0; q < 32; q++) {
                float4 wv4 = wr[q], b4 = bp[q];
                s += wv4.x*b4.x + wv4.y*b4.y + wv4.z*b4.z + wv4.w*b4.w;
            }
            s += __shfl_xor(s, 1);
            s += __shfl_xor(s, 2);
            if (part == 0) bvlG[i0 + r] = s;
        }
    } else {
        float* Cout = (z == 1) ? Mm : MT;
        #pragma unroll
        for (int i = 0; i < 2; i++)
            #pragma unroll
            for (int j = 0; j < 2; j++)
                #pragma unroll
                for (int r = 0; r < 4; r++)
                    Cout[(size_t)(i0 + rb + i*16 + r)*512 + j0 + cb + j*16] = acc[i][j][r];
        if (doT1) {
            t1a += __shfl_xor(t1a, 1);
            t1a += __shfl_xor(t1a, 2);
            if ((lane & 3) == 0) t1[j0 + jj] = t1a;
        }
        if (doT2) {
            t2a += __shfl_xor(t2a, 1);
            t2a += __shfl_xor(t2a, 2);
            if ((lane & 3) == 0) t2[i0 + jj] = t2a;
        }
        if (z == 1 && bx == 0 && by == 0 && wid == 0) {
            float s = 0.f;
            #pragma unroll
            for (int q = 0; q < 8; q++) s += bk[lane + q*64]*bq[lane + q*64];
            #pragma unroll
            for (int m = 1; m < 64; m <<= 1) s += __shfl_xor(s, m);
            if (lane == 0) *t12 = s;
        }
    }
}

// ---------------- mva: prologue reduces part[256][512] -> LDS vs[4][512] (+S0 from s0part);
//  blocks 0..31: oput[b][j] = W[j,:]·vs[b] + beta_b*bias2[j]  (fp32 and/or f16 out)
//  block 32:     cG[b] = bias3·vs[b] + beta_b*t12 ; S0G written if requested ----------------
__global__ __launch_bounds__(256) void mva_kernel(const float* __restrict__ W,
    const float* __restrict__ part, const float* __restrict__ s0part,
    const float* __restrict__ bias2, const float* __restrict__ bias3,
    const float* __restrict__ t12G,
    float* __restrict__ oput, f16* __restrict__ oput_h,
    float* __restrict__ cG, float* __restrict__ S0G)
{
    __shared__ float vs[4][512];
    __shared__ float s0s[4];
    const int t = threadIdx.x, w = t >> 6, l = t & 63;
    // prologue: column-reduce partials (each thread: 2 cols x 4 batches x 64 rows)
    {
        const int c0 = 2*t;
        #pragma unroll
        for (int b = 0; b < 4; b++) {
            float a0 = 0.f, a1 = 0.f;
            const float* base = part + (size_t)(b*64)*512 + c0;
            #pragma unroll 8
            for (int r = 0; r < 64; r++) {
                float2 vv = *(const float2*)(base + (size_t)r*512);
                a0 += vv.x; a1 += vv.y;
            }
            vs[b][c0] = a0; vs[b][c0+1] = a1;
        }
    }
    if (s0part) {   // wave w reduces s0part for batch w
        float s0 = s0part[w*64 + l];
        #pragma unroll
        for (int m = 1; m < 64; m <<= 1) s0 += __shfl_xor(s0, m);
        if (l == 0) s0s[w] = s0;
    }
    __syncthreads();
    if (blockIdx.x == 32) {
        const float4* b4 = (const float4*)(bias3 + l*8);
        float4 b0 = b4[0], b1 = b4[1];
        const float* vwp = vs[w] + l*8;
        float s = b0.x*vwp[0] + b0.y*vwp[1] + b0.z*vwp[2] + b0.w*vwp[3]
                + b1.x*vwp[4] + b1.y*vwp[5] + b1.z*vwp[6] + b1.w*vwp[7];
        #pragma unroll
        for (int m = 1; m < 64; m <<= 1) s += __shfl_xor(s, m);
        if (l == 0) {
            float beta = s0part ? s0s[w] : 4096.0f;
            cG[w] = s + beta * (*t12G);
        }
        if (S0G && t < 4) S0G[t] = s0s[t];
        return;
    }
    float vb[4][8];
    #pragma unroll
    for (int b = 0; b < 4; b++)
        #pragma unroll
        for (int q = 0; q < 8; q++) vb[b][q] = vs[b][l*8 + q];
    const int r0 = blockIdx.x*16 + w*4;
    float res[4][4];
    #pragma unroll
    for (int r = 0; r < 4; r++) {
        const float4* wr = (const float4*)(W + (size_t)(r0+r)*512 + l*8);
        float4 a = wr[0], c = wr[1];
        float wv[8] = {a.x,a.y,a.z,a.w,c.x,c.y,c.z,c.w};
        #pragma unroll
        for (int b = 0; b < 4; b++) {
            float s = 0.f;
            #pragma unroll
            for (int q = 0; q < 8; q++) s += wv[q]*vb[b][q];
            res[r][b] = s;
        }
    }
    #pragma unroll
    for (int r = 0; r < 4; r++)
        #pragma unroll
        for (int b = 0; b < 4; b++)
            #pragma unroll
            for (int m = 1; m < 64; m <<= 1) res[r][b] += __shfl_xor(res[r][b], m);
    if (l < 4) {
        const float beta = s0part ? s0s[l] : 4096.0f;
        #pragma unroll
        for (int r = 0; r < 4; r++) {
            float val = res[r][l] + beta*bias2[r0 + r];
            if (oput)   oput[l*512 + r0 + r] = val;
            if (oput_h) oput_h[l*512 + r0 + r] = (f16)val;
        }
    }
}

// ---------------- z pass (256 blocks, 64 rows each): iv = 1/(4096+(xs·h+c1)/512); partials out ----------------
__global__ __launch_bounds__(256) void z_kernel(
    const f16* __restrict__ xs_h, const float* __restrict__ hG,
    const float* __restrict__ c1G,
    float* __restrict__ zpart, float* __restrict__ s0part)
{
    __shared__ __attribute__((aligned(16))) float SMEMF[2564];  // hs 512 | yred 2048 | s0red 4
    float* hs    = SMEMF;
    float* yred  = hs + 512;
    float* s0red = yred + 2048;
    const int z = blockIdx.x, t = threadIdx.x;
    const int b = z >> 6, w = t >> 6, l = t & 63;
    hs[t] = hG[(size_t)b*512 + t]; hs[t+256] = hG[(size_t)b*512 + t + 256];
    __syncthreads();
    const float c1 = c1G[b];
    float hx[8];
    #pragma unroll
    for (int q = 0; q < 8; q++) hx[q] = hs[l*8+q];
    float yacc[8] = {0,0,0,0,0,0,0,0};
    float s0acc = 0.f;
    for (int it = 0; it < 16; it++) {
        int row = z*64 + w*16 + it;
        f16x8 v = *(const f16x8*)(xs_h + (size_t)row*512 + l*8);
        float xf[8];
        #pragma unroll
        for (int q = 0; q < 8; q++) xf[q] = (float)v[q];
        float d = 0.f;
        #pragma unroll
        for (int q = 0; q < 8; q++) d += xf[q]*hx[q];
        #pragma unroll
        for (int m = 1; m < 64; m <<= 1) d += __shfl_xor(d, m);
        float zz = 4096.0f + (d + c1)*(1.0f/512.0f);
        float iv = 1.0f/zz;
        s0acc += iv;
        #pragma unroll
        for (int q = 0; q < 8; q++) yacc[q] += iv*xf[q];
    }
    #pragma unroll
    for (int q = 0; q < 8; q++) yred[w*512 + l*8+q] = yacc[q];
    if (l == 0) s0red[w] = s0acc;
    __syncthreads();
    #pragma unroll
    for (int k = 0; k < 2; k++) {
        int c = t + k*256;
        zpart[(size_t)z*512 + c] = yred[c]+yred[512+c]+yred[1024+c]+yred[1536+c];
    }
    if (t == 0) s0part[z] = s0red[0]+s0red[1]+s0red[2]+s0red[3];
}

// ---------------- vl_gemm: out = tanh(rs*(xs@Wvl^T + bvl) + bl), rs fused via v_dot2 ----------------
__global__ __launch_bounds__(256, 2) void vl_gemm(const f16* __restrict__ A,
    const f16* __restrict__ Bt, const float* __restrict__ bvlG,
    const float* __restrict__ blG, const f16* __restrict__ uH,
    const float* __restrict__ c2G, const float* __restrict__ S0G,
    float* __restrict__ out)
{
    constexpr int K = 512;
    __shared__ f16 lA[128*32];
    __shared__ f16 lB[128*32];
    __shared__ float rsbuf[128];
    const int t = threadIdx.x;
    const int m0 = blockIdx.x*128, n0 = blockIdx.y*128;
    const int lane = t & 63, wid = t >> 6;
    const int wm = (wid & 1) << 6, wn = (wid >> 1) << 6;
    const int srow = t >> 2, skb = (t & 3) << 4;
    const long aoff0 = (long)(m0 + srow)*(K*2) + skb;
    const long aoff1 = aoff0 + 64L*(K*2);
    const long boff0 = (long)(n0 + srow)*(K*2) + skb;
    const long boff1 = boff0 + 64L*(K*2);
    char* ldsA = (char*)lA;
    char* ldsB = (char*)lB;
    const unsigned wbase = (unsigned)wid << 10;
    const char* Ab = (const char*)A;
    const char* Bb = (const char*)Bt;

    const int bat = blockIdx.x >> 5;          // 32 m-tiles per batch
    const f16* u = uH + bat*512;
    const int ku = (lane >> 4) << 3;

    f32x4 acc[4][4] = {};
    float racc[4] = {0.f,0.f,0.f,0.f};
    const int ael = (wm + (lane & 15))*32 + ku;
    const int bel = (wn + (lane & 15))*32 + ku;

    for (int k0 = 0; k0 < K; k0 += 32) {
        __syncthreads();
        const long kb = (long)k0*2;
        gl2lds16(Ab + aoff0 + kb, ldsA + wbase);
        gl2lds16(Ab + aoff1 + kb, ldsA + 4096 + wbase);
        gl2lds16(Bb + boff0 + kb, ldsB + wbase);
        gl2lds16(Bb + boff1 + kb, ldsB + 4096 + wbase);
        __syncthreads();
        f16x8 af[4], bf[4];
        #pragma unroll
        for (int i = 0; i < 4; i++) af[i] = *(const f16x8*)(lA + ael + i*512);
        #pragma unroll
        for (int j = 0; j < 4; j++) bf[j] = *(const f16x8*)(lB + bel + j*512);
        f16pack up; up.v8 = *(const f16x8*)(u + k0 + ku);
        #pragma unroll
        for (int i = 0; i < 4; i++) {
            f16pack ap; ap.v8 = af[i];
            #pragma unroll
            for (int q = 0; q < 4; q++)
                racc[i] = __builtin_amdgcn_fdot2(ap.v2[q], up.v2[q], racc[i], false);
        }
        #pragma unroll
        for (int i = 0; i < 4; i++)
            #pragma unroll
            for (int j = 0; j < 4; j++)
                acc[i][j] = __builtin_amdgcn_mfma_f32_16x16x32_f16(af[i], bf[j], acc[i][j], 0, 0, 0);
    }

    #pragma unroll
    for (int i = 0; i < 4; i++) {
        racc[i] += __shfl_xor(racc[i], 16);
        racc[i] += __shfl_xor(racc[i], 32);
    }
    const float S0 = S0G[bat], c2 = c2G[bat];
    if (wid < 2 && lane < 16) {
        #pragma unroll
        for (int i = 0; i < 4; i++)
            rsbuf[wm + i*16 + lane] = S0 + (racc[i] + c2)*(1.0f/512.0f);
    }
    __syncthreads();

    const int crb = m0 + wm + ((lane >> 4) << 2);
    const int ccb = n0 + wn + (lane & 15);
    const int lrb = wm + ((lane >> 4) << 2);
    #pragma unroll
    for (int i = 0; i < 4; i++) {
        float rsv[4];
        #pragma unroll
        for (int r = 0; r < 4; r++) rsv[r] = rsbuf[lrb + i*16 + r];
        #pragma unroll
        for (int j = 0; j < 4; j++) {
            int c = ccb + j*16;
            float bb = bvlG[c], bo = blG[c];
            #pragma unroll
            for (int r = 0; r < 4; r++) {
                float yv = rsv[r]*(acc[i][j][r] + bb) + bo;
                float e2 = __expf(2.0f*yv);
                out[(size_t)(crb + i*16 + r)*512 + c] = 1.0f - 2.0f/(e2 + 1.0f);
            }
        }
    }
}

extern "C" void kernel_launch(void* const* d_in, const int* in_sizes, int n_in,
                              void* d_out, int out_size, void* d_ws, size_t ws_size,
                              hipStream_t stream)
{
    const float* xs = (const float*)d_in[0];
    const float* Wk = (const float*)d_in[1];
    const float* bk = (const float*)d_in[2];
    const float* Wq = (const float*)d_in[3];
    const float* bq = (const float*)d_in[4];
    const float* Wv = (const float*)d_in[5];
    const float* bv = (const float*)d_in[6];
    const float* Wl = (const float*)d_in[7];
    const float* bl = (const float*)d_in[8];
    float* out = (float*)d_out;

    char* w = (char*)d_ws;
    f16*   xs_h = (f16*)w;   w += (size_t)M_*D_*2;   // 16.8 MB
    f16*   WvlH = (f16*)w;   w += (size_t)D_*D_*2;
    float* Mm   = (float*)w; w += (size_t)D_*D_*4;   // 1 MB
    float* MT   = (float*)w; w += (size_t)D_*D_*4;   // 1 MB
    float* xpart= (float*)w; w += (size_t)256*512*4; // 512 KB
    float* zpart= (float*)w; w += (size_t)256*512*4; // 512 KB
    float* s0part=(float*)w; w += (size_t)256*4;
    float* hG   = (float*)w; w += (size_t)B_*D_*4;
    f16*   uH   = (f16*)w;   w += (size_t)B_*D_*2;
    float* t1   = (float*)w; w += (size_t)D_*4;
    float* t2   = (float*)w; w += (size_t)D_*4;
    float* bvlG = (float*)w; w += (size_t)D_*4;
    float* S0G  = (float*)w; w += B_*4;
    float* c1G  = (float*)w; w += B_*4;
    float* c2G  = (float*)w; w += B_*4;
    float* t12  = (float*)w; w += 4;
    if ((size_t)(w - (char*)d_ws) > ws_size) return;  // fail loudly

    // 5 dispatches, no atomics, no memset

    k1_kernel<<<448, 256, 0, stream>>>(xs, Wv, Wk, Wq, Wl, bv, bk, bq,
        xs_h, xpart, WvlH, bvlG, Mm, MT, t1, t2, t12);

    mva_kernel<<<33, 256, 0, stream>>>(MT, xpart, nullptr, t1, t2, t12,
        hG, nullptr, c1G, nullptr);

    z_kernel<<<256, 256, 0, stream>>>(xs_h, hG, c1G, zpart, s0part);

    mva_kernel<<<33, 256, 0, stream>>>(Mm, zpart, s0part, t2, t1, t12,
        nullptr, uH, c2G, S0G);

    vl_gemm<<<dim3(128,4), 256, 0, stream>>>(xs_h, WvlH, bvlG, bl, uH, c2G, S0G, out);
}